// Round 3
// baseline (26.184 us; speedup 1.0000x reference)
//
#include <hip/hip_runtime.h>
#include <hip/hip_bf16.h>

// EmbeddedDropout: out[t, :] = scale(words[t]) * weight[words[t], :]
// scale(v) = (mask_u[v] < 0.9f) ? (1.0f/0.9f) : 0.0f   (inverted dropout, p=0.1)
//
// Shapes: weight (V=50257, D=1024) f32, mask_u (V,) f32, words (B*S=16384,) i32
// out: (16384, 1024) f32.
//
// Memory-bound gather. 2048 blocks x 8 rows/block:
//  - 8 idx/scale preloaded,
//  - 8 independent 16B loads in flight per lane (latency hiding),
//  - non-temporal stores so the write-once output doesn't evict the
//    weight table from L2/L3 (keeps gathered rows cache-resident).
//
// NOTE: __builtin_nontemporal_store requires a native vector type, not
// HIP_vector_type<float,4> — use clang ext_vector_type.

using f32x4 = __attribute__((ext_vector_type(4))) float;

constexpr int RPB = 8;  // rows per block

__global__ __launch_bounds__(256) void embed_dropout_1024(
    const float* __restrict__ weight,
    const float* __restrict__ mask_u,
    const int* __restrict__ words,
    float* __restrict__ out,
    int n_tokens)
{
    constexpr int D = 1024;
    const int row0 = blockIdx.x * RPB;
    const int t = threadIdx.x;                 // 0..255, one f32x4 per row

    int   idx[RPB];
    float scl[RPB];
#pragma unroll
    for (int r = 0; r < RPB; ++r) {
        const int row = row0 + r;
        idx[r] = (row < n_tokens) ? words[row] : 0;
        scl[r] = (mask_u[idx[r]] < 0.9f) ? (1.0f / 0.9f) : 0.0f;
    }

    // Issue all row loads first — 8 outstanding dwordx4 per lane.
    f32x4 v[RPB];
#pragma unroll
    for (int r = 0; r < RPB; ++r) {
        const f32x4* src =
            reinterpret_cast<const f32x4*>(weight + (size_t)idx[r] * D);
        v[r] = src[t];
    }

#pragma unroll
    for (int r = 0; r < RPB; ++r) {
        const int row = row0 + r;
        if (row < n_tokens) {
            f32x4 w = v[r] * scl[r];
            f32x4* dst = reinterpret_cast<f32x4*>(out + (size_t)row * D);
            __builtin_nontemporal_store(w, &dst[t]);
        }
    }
}

// Generic fallback for unexpected D (kept correct for any D % 4 == 0).
__global__ __launch_bounds__(256) void embed_dropout_generic(
    const float* __restrict__ weight,
    const float* __restrict__ mask_u,
    const int* __restrict__ words,
    float* __restrict__ out,
    int D, int n_tokens)
{
    const int row = blockIdx.x;
    if (row >= n_tokens) return;
    const int idx = words[row];
    const float scale = (mask_u[idx] < 0.9f) ? (1.0f / 0.9f) : 0.0f;
    const f32x4* src = reinterpret_cast<const f32x4*>(weight + (size_t)idx * (size_t)D);
    f32x4* dst = reinterpret_cast<f32x4*>(out + (size_t)row * (size_t)D);
    for (int i = threadIdx.x; i < (D >> 2); i += blockDim.x) {
        f32x4 v = src[i] * scale;
        __builtin_nontemporal_store(v, &dst[i]);
    }
}

extern "C" void kernel_launch(void* const* d_in, const int* in_sizes, int n_in,
                              void* d_out, int out_size, void* d_ws, size_t ws_size,
                              hipStream_t stream) {
    const float* weight = (const float*)d_in[0];
    const float* mask_u = (const float*)d_in[1];
    const int*   words  = (const int*)d_in[2];
    float* out = (float*)d_out;

    const int V = in_sizes[1];              // mask_u has V elements
    const int D = in_sizes[0] / V;          // 1024
    const int n_tokens = in_sizes[2];       // 16384
    (void)out_size; (void)d_ws; (void)ws_size; (void)n_in;

    if (D == 1024) {
        dim3 grid((n_tokens + RPB - 1) / RPB);
        embed_dropout_1024<<<grid, dim3(256), 0, stream>>>(
            weight, mask_u, words, out, n_tokens);
    } else {
        embed_dropout_generic<<<dim3(n_tokens), dim3(256), 0, stream>>>(
            weight, mask_u, words, out, D, n_tokens);
    }
}

// Round 4
// 25.973 us; speedup vs baseline: 1.0081x; 1.0081x over previous
//
#include <hip/hip_runtime.h>
#include <hip/hip_bf16.h>

// EmbeddedDropout: out[t, :] = scale(words[t]) * weight[words[t], :]
// scale(v) = (mask_u[v] < 0.9f) ? (1.0f/0.9f) : 0.0f   (inverted dropout, p=0.1)
//
// Shapes: weight (V=50257, D=1024) f32, mask_u (V,) f32, words (B*S=16384,) i32
// out: (16384, 1024) f32.
//
// Memory-bound gather. The gathered working set (~57 MB unique rows) is FIXED
// across graph replays and fits L3 (256 MB) — but only if the 64 MB/replay
// output write stream doesn't churn the cache. __builtin_nontemporal_store
// (nt only) was neutral; this round: inline-asm stores with "sc0 sc1 nt"
// (device-scope streaming, no L2/MALL allocate) so weight rows stay resident.

using f32x4 = __attribute__((ext_vector_type(4))) float;

constexpr int RPB = 8;  // rows per block

__global__ __launch_bounds__(256) void embed_dropout_1024(
    const float* __restrict__ weight,
    const float* __restrict__ mask_u,
    const int* __restrict__ words,
    float* __restrict__ out,
    int n_tokens)
{
    constexpr int D = 1024;
    const int row0 = blockIdx.x * RPB;
    const int t = threadIdx.x;                 // 0..255, one f32x4 per row

    int   idx[RPB];
    float scl[RPB];
#pragma unroll
    for (int r = 0; r < RPB; ++r) {
        const int row = row0 + r;
        idx[r] = (row < n_tokens) ? words[row] : 0;
        scl[r] = (mask_u[idx[r]] < 0.9f) ? (1.0f / 0.9f) : 0.0f;
    }

    // Issue all row loads first — 8 outstanding dwordx4 per lane.
    f32x4 v[RPB];
#pragma unroll
    for (int r = 0; r < RPB; ++r) {
        const f32x4* src =
            reinterpret_cast<const f32x4*>(weight + (size_t)idx[r] * D);
        v[r] = src[t];
    }

#pragma unroll
    for (int r = 0; r < RPB; ++r) {
        const int row = row0 + r;
        if (row < n_tokens) {
            f32x4 w = v[r] * scl[r];
            float* dst = out + (size_t)row * D + (size_t)t * 4;
            // Streaming store: no-allocate in L2/MALL (sc0 sc1 nt).
            asm volatile("global_store_dwordx4 %0, %1, off sc0 sc1 nt"
                         :
                         : "v"(dst), "v"(w)
                         : "memory");
        }
    }
}

// Generic fallback for unexpected D (kept correct for any D % 4 == 0).
__global__ __launch_bounds__(256) void embed_dropout_generic(
    const float* __restrict__ weight,
    const float* __restrict__ mask_u,
    const int* __restrict__ words,
    float* __restrict__ out,
    int D, int n_tokens)
{
    const int row = blockIdx.x;
    if (row >= n_tokens) return;
    const int idx = words[row];
    const float scale = (mask_u[idx] < 0.9f) ? (1.0f / 0.9f) : 0.0f;
    const f32x4* src = reinterpret_cast<const f32x4*>(weight + (size_t)idx * (size_t)D);
    f32x4* dst = reinterpret_cast<f32x4*>(out + (size_t)row * (size_t)D);
    for (int i = threadIdx.x; i < (D >> 2); i += blockDim.x) {
        f32x4 v = src[i] * scale;
        __builtin_nontemporal_store(v, &dst[i]);
    }
}

extern "C" void kernel_launch(void* const* d_in, const int* in_sizes, int n_in,
                              void* d_out, int out_size, void* d_ws, size_t ws_size,
                              hipStream_t stream) {
    const float* weight = (const float*)d_in[0];
    const float* mask_u = (const float*)d_in[1];
    const int*   words  = (const int*)d_in[2];
    float* out = (float*)d_out;

    const int V = in_sizes[1];              // mask_u has V elements
    const int D = in_sizes[0] / V;          // 1024
    const int n_tokens = in_sizes[2];       // 16384
    (void)out_size; (void)d_ws; (void)ws_size; (void)n_in;

    if (D == 1024) {
        dim3 grid((n_tokens + RPB - 1) / RPB);
        embed_dropout_1024<<<grid, dim3(256), 0, stream>>>(
            weight, mask_u, words, out, n_tokens);
    } else {
        embed_dropout_generic<<<dim3(n_tokens), dim3(256), 0, stream>>>(
            weight, mask_u, words, out, D, n_tokens);
    }
}